// Round 1
// baseline (272.669 us; speedup 1.0000x reference)
//
#include <hip/hip_runtime.h>
#include <math.h>

#define NSEQ 2048
#define EPSF 1e-8f
#define INV2R2 0.35355339059327373f
#define INVR2  0.7071067811865476f

// ---------- compile-time Leray conv taps ----------
// Jacobi: p_{n+1} = M p_n - 0.5 b, M = avg(neighbors), p_0 = 0, 50 iters
// => p = K * b, K = -0.5 * sum_{i=0}^{49} M^i   (circulant, support |j|<=49)
// leray(u) = u - grad1(K * div1(u)) = conv(LK, u), LK_o = delta_o - (K_{o+1} - 2K_o + K_{o-1})
// Leray is self-adjoint (LK symmetric) -> backward uses same conv.
struct TapsF { float v[101]; };

constexpr TapsF make_tapsf() {
  TapsF t{};
  double K[99] = {};
  for (int j = -49; j <= 49; ++j) {
    int aj = j < 0 ? -j : j;
    double term = 1.0;
    for (int q = 0; q < aj; ++q) term *= 0.5;      // C(aj, m0)/2^aj = 1/2^aj
    double sum = term;
    for (int i = aj + 2; i <= 49; i += 2) {
      int m = (i + j) / 2;
      term *= (double)((i - 1) * i) / (4.0 * (double)m * (double)(i - m));
      sum += term;
    }
    K[j + 49] = -0.5 * sum;
  }
  for (int o = -50; o <= 50; ++o) {
    double km1 = (o - 1 >= -49 && o - 1 <= 49) ? K[o - 1 + 49] : 0.0;
    double k0  = (o     >= -49 && o     <= 49) ? K[o + 49]     : 0.0;
    double kp1 = (o + 1 >= -49 && o + 1 <= 49) ? K[o + 1 + 49] : 0.0;
    double T = kp1 - 2.0 * k0 + km1;
    t.v[o + 50] = (float)(((o == 0) ? 1.0 : 0.0) - T);
  }
  return t;
}
constexpr TapsF LKF = make_tapsf();

// ---------- reduction helpers (256-thread block = 4 waves) ----------
__device__ __forceinline__ float wave_sum(float x) {
#pragma unroll
  for (int m = 1; m < 64; m <<= 1) x += __shfl_xor(x, m, 64);
  return x;
}
__device__ __forceinline__ float wave_max(float x) {
#pragma unroll
  for (int m = 1; m < 64; m <<= 1) x = fmaxf(x, __shfl_xor(x, m, 64));
  return x;
}
__device__ __forceinline__ float block_sum(float x, float* red, int tid, int& gen) {
  float w = wave_sum(x);
  int slot = (gen & 15) * 8; gen++;
  if ((tid & 63) == 0) red[slot + (tid >> 6)] = w;
  __syncthreads();
  return red[slot] + red[slot + 1] + red[slot + 2] + red[slot + 3];
}
__device__ __forceinline__ float block_max(float x, float* red, int tid, int& gen) {
  float w = wave_max(x);
  int slot = (gen & 15) * 8; gen++;
  if ((tid & 63) == 0) red[slot + (tid >> 6)] = w;
  __syncthreads();
  return fmaxf(fmaxf(red[slot], red[slot + 1]), fmaxf(red[slot + 2], red[slot + 3]));
}
__device__ __forceinline__ void block_sum2(float a, float b, float* red, int tid, int& gen,
                                           float& oa, float& ob) {
  float wa = wave_sum(a), wb = wave_sum(b);
  int slot = (gen & 15) * 8; gen++;
  if ((tid & 63) == 0) { int w = tid >> 6; red[slot + w] = wa; red[slot + 4 + w] = wb; }
  __syncthreads();
  oa = red[slot] + red[slot + 1] + red[slot + 2] + red[slot + 3];
  ob = red[slot + 4] + red[slot + 5] + red[slot + 6] + red[slot + 7];
}

// ---------- 101-tap circular conv (leray), conflict-free via transposed staging ----------
// cb[loc(i)] = src[i], loc(i) = ((i&7)<<8)|(i>>3): window reads across lanes are stride-1.
template <int MODE>  // 0: dst[i] = conv(src)[i];  1: dst[i] -= 0.1f*conv(src)[i]
__device__ __forceinline__ void conv_apply(float* __restrict__ dst, const float* __restrict__ src,
                                           float* __restrict__ cb, int tid) {
  __syncthreads();
#pragma unroll
  for (int m = 0; m < 8; ++m) {
    int L = tid + 256 * m;
    int idx = ((L & 255) << 3) | (L >> 8);   // inverse of loc()
    cb[L] = src[idx];
  }
  __syncthreads();
  const int base = tid << 3;
  float acc[8] = {0.f, 0.f, 0.f, 0.f, 0.f, 0.f, 0.f, 0.f};
  float w[8];
  int ip = (base - 50) & (NSEQ - 1);
#pragma unroll
  for (int j = 0; j < 7; ++j) {
    w[j] = cb[((ip & 7) << 8) | (ip >> 3)];
    ip = (ip + 1) & (NSEQ - 1);
  }
#pragma unroll
  for (int n = 0; n < 101; ++n) {
    w[7] = cb[((ip & 7) << 8) | (ip >> 3)];
    ip = (ip + 1) & (NSEQ - 1);
    const float tap = LKF.v[100 - n];
#pragma unroll
    for (int j = 0; j < 8; ++j) acc[j] = fmaf(tap, w[j], acc[j]);
#pragma unroll
    for (int j = 0; j < 7; ++j) w[j] = w[j + 1];
  }
#pragma unroll
  for (int j = 0; j < 8; ++j) {
    if (MODE == 0) dst[base + j] = acc[j];
    else           dst[base + j] -= 0.1f * acc[j];
  }
  __syncthreads();
}

// ---------- kernel A: rho_unscaled (L2 of DWT rows) + per_token ----------
__global__ __launch_bounds__(256) void kA(const float* __restrict__ x,
                                          const float* __restrict__ wv,
                                          float* __restrict__ rho_us,
                                          float* __restrict__ pt) {
  const int blk = blockIdx.x;
  const int b = blk >> 8;
  const int g = blk & 255;
  const float* xb = x + (((size_t)b * NSEQ) + (size_t)g * 8) * 2048;
  const int tid = threadIdx.x;
  float sq[8] = {0.f, 0.f, 0.f, 0.f, 0.f, 0.f, 0.f, 0.f};
  float pp[8] = {0.f, 0.f, 0.f, 0.f, 0.f, 0.f, 0.f, 0.f};
  for (int c = tid * 4; c < 2048; c += 1024) {
    float4 w4 = *(const float4*)(wv + c);
    float wj[4] = {w4.x, w4.y, w4.z, w4.w};
    float xv[8][4];
#pragma unroll
    for (int r = 0; r < 8; ++r) {
      float4 t = *(const float4*)(xb + (size_t)r * 2048 + c);
      xv[r][0] = t.x; xv[r][1] = t.y; xv[r][2] = t.z; xv[r][3] = t.w;
    }
#pragma unroll
    for (int j = 0; j < 4; ++j) {
      float x0 = xv[0][j], x1 = xv[1][j], x2 = xv[2][j], x3 = xv[3][j];
      float x4 = xv[4][j], x5 = xv[5][j], x6 = xv[6][j], x7 = xv[7][j];
      float t01 = x0 + x1, t23 = x2 + x3, t45 = x4 + x5, t67 = x6 + x7;
      float a = t01 + t23, bb = t45 + t67;
      float c3 = a + bb, d3 = a - bb, d2a = t01 - t23, d2b = t45 - t67;
      float d10 = x0 - x1, d11 = x2 - x3, d12 = x4 - x5, d13 = x6 - x7;
      sq[0] += c3 * c3;  sq[1] += d3 * d3;  sq[2] += d2a * d2a; sq[3] += d2b * d2b;
      sq[4] += d10 * d10; sq[5] += d11 * d11; sq[6] += d12 * d12; sq[7] += d13 * d13;
      float w = wj[j];
      pp[0] += x0 * w; pp[1] += x1 * w; pp[2] += x2 * w; pp[3] += x3 * w;
      pp[4] += x4 * w; pp[5] += x5 * w; pp[6] += x6 * w; pp[7] += x7 * w;
    }
  }
  __shared__ float sred[4][16];
  float vals[16];
#pragma unroll
  for (int q = 0; q < 8; ++q) vals[q] = sq[q];
#pragma unroll
  for (int q = 0; q < 8; ++q) vals[8 + q] = pp[q];
#pragma unroll
  for (int q = 0; q < 16; ++q) vals[q] = wave_sum(vals[q]);
  int lane = tid & 63, wid = tid >> 6;
  if (lane == 0) {
#pragma unroll
    for (int q = 0; q < 16; ++q) sred[wid][q] = vals[q];
  }
  __syncthreads();
  if (tid < 16) {
    float s = sred[0][tid] + sred[1][tid] + sred[2][tid] + sred[3][tid];
    if (tid < 8) {
      float scale = (tid < 2) ? 0.125f : ((tid < 4) ? 0.25f : 0.5f);
      int pos = (tid == 0) ? g : (tid == 1) ? (256 + g)
               : (tid < 4) ? (512 + 2 * g + (tid - 2)) : (1024 + 4 * g + (tid - 4));
      rho_us[b * NSEQ + pos] = sqrtf(s * scale);
    } else {
      pt[b * NSEQ + 8 * g + (tid - 8)] = s;
    }
  }
}

// ---------- kernel B: the serial dynamics (one block per batch) ----------
__global__ __launch_bounds__(256, 1) void kB(const float* __restrict__ rho_us,
                                             const float* __restrict__ pt,
                                             const float* __restrict__ phi,
                                             float* __restrict__ rho_f) {
  extern __shared__ float sm[];
  float* v   = sm;
  float* rho = sm + NSEQ;
  float* u   = sm + 2 * NSEQ;
  float* up  = sm + 3 * NSEQ;
  float* y0  = sm + 4 * NSEQ;
  float* y1  = sm + 5 * NSEQ;
  float* y2  = sm + 6 * NSEQ;
  float* y3  = sm + 7 * NSEQ;
  float* yb  = sm + 8 * NSEQ;
  float* cb  = sm + 9 * NSEQ;
  float* red = sm + 10 * NSEQ;  // 128 floats
  const int tid = threadIdx.x;
  const int b = blockIdx.x;
  int gen = 0;
  const float CFL_ = 0.4f;

  // ---- v = normalize(|dwt1d(per_token)|*sqrt(D)) ----
  {
    const float* ptb = pt + b * NSEQ;
    float vl[8]; float part = 0.f;
#pragma unroll
    for (int m = 0; m < 8; ++m) {
      int s = tid + 256 * m;
      float c;
      if (s < 256) {
        int r = s * 8;
        float t01 = ptb[r] + ptb[r+1], t23 = ptb[r+2] + ptb[r+3];
        float t45 = ptb[r+4] + ptb[r+5], t67 = ptb[r+6] + ptb[r+7];
        c = ((t01 + t23) + (t45 + t67)) * INV2R2;
      } else if (s < 512) {
        int r = (s - 256) * 8;
        float t01 = ptb[r] + ptb[r+1], t23 = ptb[r+2] + ptb[r+3];
        float t45 = ptb[r+4] + ptb[r+5], t67 = ptb[r+6] + ptb[r+7];
        c = ((t01 + t23) - (t45 + t67)) * INV2R2;
      } else if (s < 1024) {
        int r = (s - 512) * 4;
        c = ((ptb[r] + ptb[r+1]) - (ptb[r+2] + ptb[r+3])) * 0.5f;
      } else {
        int r = (s - 1024) * 2;
        c = (ptb[r] - ptb[r+1]) * INVR2;
      }
      float val = sqrtf(2048.0f * c * c) + EPSF;
      vl[m] = val; part += val;
    }
    float sv = block_sum(part, red, tid, gen);
    float inv = 1.0f / sv;
#pragma unroll
    for (int m = 0; m < 8; ++m) v[tid + 256 * m] = vl[m] * inv;
  }
  // ---- rho = normalize(rho_us) ----
  {
    const float* rb = rho_us + b * NSEQ;
    float rl[8]; float part = 0.f;
#pragma unroll
    for (int m = 0; m < 8; ++m) { float r = rb[tid + 256 * m] + EPSF; rl[m] = r; part += r; }
    float sr = block_sum(part, red, tid, gen);
    float inv = 1.f / sr;
#pragma unroll
    for (int m = 0; m < 8; ++m) rho[tid + 256 * m] = rl[m] * inv;
  }
  __syncthreads();

  for (int k = 0; k < 3; ++k) {
    // ---- reaction ----
    {
      float tl[8]; float part = 0.f;
#pragma unroll
      for (int m = 0; m < 8; ++m) {
        int i = tid + 256 * m;
        float r = rho[i];
        float t = r * expf(-0.1f * (phi[i] + logf(r)));
        float t2 = fabsf(t) + EPSF;
        tl[m] = t2; part += t2;
      }
      float s = block_sum(part, red, tid, gen);
      float inv = 1.f / s;
#pragma unroll
      for (int m = 0; m < 8; ++m) rho[tid + 256 * m] = tl[m] * inv;
    }
    // ---- mpc: u = grad1(v) ----
#pragma unroll
    for (int m = 0; m < 8; ++m) {
      int i = tid + 256 * m; int ip1 = (i + 1) & (NSEQ - 1);
      u[i] = v[ip1] - v[i];
    }
    for (int step = 0; step < 5; ++step) {
      conv_apply<0>(up, u, cb, tid);  // up = leray(u)
      float part = 0.f;
#pragma unroll
      for (int m = 0; m < 8; ++m) part = fmaxf(part, fabsf(up[tid + 256 * m]));
      float mx = block_max(part, red, tid, gen);
      float dt = CFL_ / (mx + EPSF);
      // ---- forward rollout, r_t kept implicitly as (|y_{t-1}|+eps)/s_{t-1} ----
      float sarr[4]; float spv = 1.f;
#pragma unroll
      for (int t = 0; t < 4; ++t) {
        const float* yp = (t == 1) ? y0 : (t == 2) ? y1 : y2;
        float* yw = (t == 0) ? y0 : (t == 1) ? y1 : (t == 2) ? y2 : y3;
        float invp = 1.f / spv;
        float part2 = 0.f;
#pragma unroll
        for (int m = 0; m < 8; ++m) {
          int i = tid + 256 * m, im1 = (i - 1) & (NSEQ - 1), ip1 = (i + 1) & (NSEQ - 1);
          float ri, rim1, rip1;
          if (t == 0) { ri = rho[i]; rim1 = rho[im1]; rip1 = rho[ip1]; }
          else {
            ri   = (fabsf(yp[i])   + EPSF) * invp;
            rim1 = (fabsf(yp[im1]) + EPSF) * invp;
            rip1 = (fabsf(yp[ip1]) + EPSF) * invp;
          }
          float ui = up[i], um = up[im1];
          float Fi = ui > 0.f ? ui * ri : ui * rip1;
          float Fm = um > 0.f ? um * rim1 : um * ri;
          float yv = ri - dt * (Fi - Fm);
          yw[i] = yv;
          part2 += fabsf(yv) + EPSF;
        }
        sarr[t] = block_sum(part2, red, tid, gen);
        spv = sarr[t];
      }
      // ---- backward ----
      float wreg[8], upbar[8];
      float dtb_part = 0.f, ntie_part = 0.f, part3 = 0.f;
      float inv3 = 1.f / sarr[3];
#pragma unroll
      for (int m = 0; m < 8; ++m) {
        int i = tid + 256 * m;
        upbar[m] = 0.f;
        wreg[m] = (1.f - v[i]) * 0.125f;                 // d cost/d r4 (mean over B=8)
        part3 += wreg[m] * (fabsf(y3[i]) + EPSF) * inv3; // wbar . r4
        ntie_part += (fabsf(up[i]) == mx) ? 1.f : 0.f;
      }
      float dot, ntie;
      block_sum2(part3, ntie_part, red, tid, gen, dot, ntie);
#pragma unroll
      for (int t = 3; t >= 0; --t) {
        const float* yt = (t == 0) ? y0 : (t == 1) ? y1 : (t == 2) ? y2 : y3;
        const float* yp = (t == 1) ? y0 : (t == 2) ? y1 : y2;
        float invst = 1.f / sarr[t];
        float invp = (t > 0) ? 1.f / sarr[t - 1] : 0.f;
        // pass A: ybar
#pragma unroll
        for (int m = 0; m < 8; ++m) {
          int i = tid + 256 * m;
          float yv = yt[i];
          float sg = (yv > 0.f) ? 1.f : ((yv < 0.f) ? -1.f : 0.f);
          yb[i] = sg * (wreg[m] - dot) * invst;
        }
        __syncthreads();
        // pass B: new wbar, upbar, dtbar, next dot
        float dotn = 0.f;
#pragma unroll
        for (int m = 0; m < 8; ++m) {
          int i = tid + 256 * m, im1 = (i - 1) & (NSEQ - 1), ip1 = (i + 1) & (NSEQ - 1);
          float ri, rim1, rip1;
          if (t == 0) { ri = rho[i]; rim1 = rho[im1]; rip1 = rho[ip1]; }
          else {
            ri   = (fabsf(yp[i])   + EPSF) * invp;
            rim1 = (fabsf(yp[im1]) + EPSF) * invp;
            rip1 = (fabsf(yp[ip1]) + EPSF) * invp;
          }
          float ui = up[i], um = up[im1];
          float ybi = yb[i], ybm = yb[im1], ybp = yb[ip1];
          float Fbi = dt * (ybp - ybi);
          float Fbm = dt * (ybi - ybm);
          float wn = ybi;
          if (ui > 0.f)    wn += Fbi * ui;
          if (!(um > 0.f)) wn += Fbm * um;
          upbar[m] += Fbi * (ui > 0.f ? ri : rip1);
          float Fi = ui > 0.f ? ui * ri : ui * rip1;
          float Fm = um > 0.f ? um * rim1 : um * ri;
          dtb_part -= ybi * (Fi - Fm);
          if (t > 0) dotn += wn * ri;
          wreg[m] = wn;
        }
        if (t > 0) dot = block_sum(dotn, red, tid, gen);
      }
      float dtbar = block_sum(dtb_part, red, tid, gen);
      float md = mx + EPSF;
      float mbar = dtbar * (-CFL_ / (md * md));
      float tiesc = mbar / ntie;
#pragma unroll
      for (int m = 0; m < 8; ++m) {
        int i = tid + 256 * m;
        float ui = up[i];
        if (fabsf(ui) == mx) {
          float sg = (ui > 0.f) ? 1.f : ((ui < 0.f) ? -1.f : 0.f);
          upbar[m] += tiesc * sg;
        }
        yb[i] = upbar[m];
      }
      conv_apply<1>(u, yb, cb, tid);  // u -= 0.1 * leray(upbar)  (self-adjoint)
    }
    // ---- outer: u = leray(u); dt; rho = normalize(advect(rho,u,dt,kappa)) ----
    conv_apply<0>(up, u, cb, tid);
    float part = 0.f;
#pragma unroll
    for (int m = 0; m < 8; ++m) part = fmaxf(part, fabsf(up[tid + 256 * m]));
    float mx = block_max(part, red, tid, gen);
    float dt = CFL_ / (mx + EPSF);
    float kap = (k == 0) ? 0.01f : ((k == 1) ? 0.005f : 0.0f);
    float ylc[8]; float p2 = 0.f;
#pragma unroll
    for (int m = 0; m < 8; ++m) {
      int i = tid + 256 * m, im1 = (i - 1) & (NSEQ - 1), ip1 = (i + 1) & (NSEQ - 1);
      float ri = rho[i], rim1 = rho[im1], rip1 = rho[ip1];
      float ui = up[i], um = up[im1];
      float Fi = ui > 0.f ? ui * ri : ui * rip1;
      float Fm = um > 0.f ? um * rim1 : um * ri;
      float yv = ri - dt * (Fi - Fm) + kap * dt * (rip1 + rim1 - 2.f * ri);
      ylc[m] = yv; p2 += fabsf(yv) + EPSF;
    }
    float s = block_sum(p2, red, tid, gen);
    float inv = 1.f / s;
#pragma unroll
    for (int m = 0; m < 8; ++m) rho[tid + 256 * m] = (fabsf(ylc[m]) + EPSF) * inv;
    __syncthreads();
  }
  // ---- final: rho_f = (rho + 0.1 v)/sum ----
  {
    float fl[8]; float part = 0.f;
#pragma unroll
    for (int m = 0; m < 8; ++m) {
      int i = tid + 256 * m;
      float f = rho[i] + 0.1f * v[i];
      fl[m] = f; part += f;
    }
    float s = block_sum(part, red, tid, gen);
    float inv = 1.f / s;
#pragma unroll
    for (int m = 0; m < 8; ++m) rho_f[b * NSEQ + tid + 256 * m] = fl[m] * inv;
  }
}

// ---------- kernel C: out = IDWT3(rho_f[:,:,None] * band_w[BAND_IDX]) ----------
__global__ __launch_bounds__(256) void kC(const float* __restrict__ rho_f,
                                          const float* __restrict__ bw,
                                          float* __restrict__ out) {
  const int blk = blockIdx.x;
  const int b = blk >> 8;
  const int g = blk & 255;
  __shared__ float q[8];
  if (threadIdx.x < 8) {
    int t = threadIdx.x;
    const float* rb = rho_f + b * NSEQ;
    float val;
    if (t == 0)      val = rb[g] * INV2R2;                   // a3, band 0
    else if (t == 1) val = rb[256 + g] * INV2R2;             // d3, band 1
    else if (t < 4)  val = rb[512 + 2 * g + (t - 2)] * 0.5f; // d2, band 2
    else             val = rb[1024 + 4 * g + (t - 4)] * INVR2; // d1, band 3
    q[t] = val;
  }
  __syncthreads();
  float* ob = out + (((size_t)b * NSEQ) + (size_t)g * 8) * 2048;
  for (int c = threadIdx.x * 4; c < 2048; c += 1024) {
    float4 B0 = *(const float4*)(bw + c);
    float4 B1 = *(const float4*)(bw + 2048 + c);
    float4 B2 = *(const float4*)(bw + 4096 + c);
    float4 B3 = *(const float4*)(bw + 6144 + c);
    float b0[4] = {B0.x, B0.y, B0.z, B0.w};
    float b1[4] = {B1.x, B1.y, B1.z, B1.w};
    float b2[4] = {B2.x, B2.y, B2.z, B2.w};
    float b3[4] = {B3.x, B3.y, B3.z, B3.w};
    float o[8][4];
#pragma unroll
    for (int cc = 0; cc < 4; ++cc) {
      float pa = q[0] * b0[cc], pd3 = q[1] * b1[cc];
      float p2a = q[2] * b2[cc], p2b = q[3] * b2[cc];
      float e0 = pa + pd3, e1 = pa - pd3;
      float f0 = e0 + p2a, f1 = e0 - p2a, f2 = e1 + p2b, f3 = e1 - p2b;
      float g0 = q[4] * b3[cc], g1 = q[5] * b3[cc], g2 = q[6] * b3[cc], g3 = q[7] * b3[cc];
      o[0][cc] = f0 + g0; o[1][cc] = f0 - g0;
      o[2][cc] = f1 + g1; o[3][cc] = f1 - g1;
      o[4][cc] = f2 + g2; o[5][cc] = f2 - g2;
      o[6][cc] = f3 + g3; o[7][cc] = f3 - g3;
    }
#pragma unroll
    for (int j = 0; j < 8; ++j) {
      float4 t = make_float4(o[j][0], o[j][1], o[j][2], o[j][3]);
      *(float4*)(ob + (size_t)j * 2048 + c) = t;
    }
  }
}

#define SMEM_B ((10 * NSEQ + 128) * sizeof(float))

extern "C" void kernel_launch(void* const* d_in, const int* in_sizes, int n_in,
                              void* d_out, int out_size, void* d_ws, size_t ws_size,
                              hipStream_t stream) {
  (void)in_sizes; (void)n_in; (void)out_size; (void)ws_size;
  const float* x   = (const float*)d_in[0];
  const float* wv  = (const float*)d_in[1];
  const float* phi = (const float*)d_in[2];
  const float* bw  = (const float*)d_in[3];
  float* out = (float*)d_out;
  float* rho_us = (float*)d_ws;
  float* pt     = rho_us + 8 * NSEQ;
  float* rho_f  = pt + 8 * NSEQ;

  hipFuncSetAttribute((const void*)kB, hipFuncAttributeMaxDynamicSharedMemorySize,
                      (int)SMEM_B);

  kA<<<dim3(2048), dim3(256), 0, stream>>>(x, wv, rho_us, pt);
  kB<<<dim3(8), dim3(256), SMEM_B, stream>>>(rho_us, pt, phi, rho_f);
  kC<<<dim3(2048), dim3(256), 0, stream>>>(rho_f, bw, out);
}